// Round 8
// baseline (262.352 us; speedup 1.0000x reference)
//
#include <hip/hip_runtime.h>
#include <hip/hip_bf16.h>

#define D_MODEL 4096
#define NTOK    8192   // B*S = 4*2048
#define SEQ     2048

typedef short bf16x8 __attribute__((ext_vector_type(8)));  // 8 bf16 in 4 VGPRs
typedef float f32x4  __attribute__((ext_vector_type(4)));

__device__ __forceinline__ short f2bf(float x) {
  __hip_bfloat16 h = __float2bfloat16(x);
  return *reinterpret_cast<short*>(&h);
}
__device__ __forceinline__ float bfs2f(unsigned short u) {
  unsigned int x = ((unsigned int)u) << 16;
  float f;
  __builtin_memcpy(&f, &x, 4);
  return f;
}
__device__ __forceinline__ float bf2f(const void* p, size_t i) {
  return bfs2f(((const unsigned short*)p)[i]);
}

// Async global->LDS, 16B per lane. LDS dest is the WAVE-UNIFORM base
// (HW adds lane*16); global src is per-lane (guide m104/m173).
__device__ __forceinline__ void gload_lds16(const void* g, void* l) {
  __builtin_amdgcn_global_load_lds(
      (__attribute__((address_space(1))) void*)(g),
      (__attribute__((address_space(3))) void*)(l), 16, 0, 0);
}

// ---------------------------------------------------------------------------
// Wave-level dtype sniff (confirmed: hidden=bf16, weights=f32; kept for
// robustness). Returns 1 -> bf16[], 0 -> float[]. Wave-uniform result.
// ---------------------------------------------------------------------------
__device__ __forceinline__ int sniff_wave(const unsigned short* p, int n) {
  int lane = threadIdx.x & 63;
  int S = n / 2 < 64 ? n / 2 : 64;
  bool act = lane < S;
  unsigned short ve = 0, vo = 0;
  if (act) { ve = p[2 * lane]; vo = p[2 * lane + 1]; }
  int ee = (ve >> 7) & 0xFF, eo = (vo >> 7) & 0xFF;
  bool ve_band   = (ve == 0) || (ve == 0x8000) || (ee >= 96 && ee <= 141);
  bool vo_bandnz = (vo != 0) && (vo != 0x8000) && (eo >= 96 && eo <= 141);
  int zp = __popcll(__ballot(act && ve == 0 && vo == 0));
  int ob = __popcll(__ballot(act && ve == 0 && vo_bandnz));
  int eb = __popcll(__ballot(act && ve_band));
  if (zp == S) return 1;
  if (4 * ob >= 3 * S) return 0;   // f32 storage of bf16-rounded values
  if (4 * eb >= 3 * S) return 1;   // true bf16
  return 0;                        // raw f32
}

__device__ __forceinline__ float decode_lam(const void* lamp) {
  unsigned short l0 = *(const unsigned short*)lamp;
  int le = (l0 >> 7) & 0xFF;
  if (l0 != 0 && l0 != 0x8000 && le >= 96 && le <= 141)
    return bfs2f(l0);
  return *(const float*)lamp;
}
__device__ __forceinline__ float decode_b2(const void* p) {
  unsigned short c0 = *(const unsigned short*)p;
  int ce = (c0 >> 7) & 0xFF;
  if (c0 == 0) return 0.0f;
  if (c0 != 0x8000 && ce >= 96 && ce <= 141)
    return bfs2f(c0);
  return *(const float*)p;
}

// ---------------------------------------------------------------------------
// Kernel 1: fold W_fiber into W1 -> W1_eff[64][4096] bf16 (vectorized).
// ---------------------------------------------------------------------------
__global__ __launch_bounds__(256) void fold_w1(const void* __restrict__ W1v,
                                               const void* __restrict__ Wfv,
                                               short* __restrict__ W1eff) {
  int n = blockIdx.x;  // 0..63
  int fw1 = sniff_wave((const unsigned short*)W1v, 64 * 4112);
  int fwf = sniff_wave((const unsigned short*)Wfv, 16 * D_MODEL);
  __shared__ float w1b[16];
  if (threadIdx.x < 16) {
    size_t idx = (size_t)n * 4112 + 4096 + threadIdx.x;
    w1b[threadIdx.x] = fw1 ? bf2f(W1v, idx) : ((const float*)W1v)[idx];
  }
  __syncthreads();
  for (int it = 0; it < 4; ++it) {
    int k0 = it * 1024 + threadIdx.x * 4;
    size_t idx = (size_t)n * 4112 + k0;
    float v0, v1, v2, v3;
    if (fw1) {
      ushort4 u = *(const ushort4*)((const unsigned short*)W1v + idx);
      v0 = bfs2f(u.x); v1 = bfs2f(u.y); v2 = bfs2f(u.z); v3 = bfs2f(u.w);
    } else {
      float4 f = *(const float4*)((const float*)W1v + idx);
      v0 = f.x; v1 = f.y; v2 = f.z; v3 = f.w;
    }
#pragma unroll
    for (int f = 0; f < 16; ++f) {
      size_t wi = (size_t)f * D_MODEL + k0;
      float w0, w1_, w2_, w3_;
      if (fwf) {
        ushort4 u = *(const ushort4*)((const unsigned short*)Wfv + wi);
        w0 = bfs2f(u.x); w1_ = bfs2f(u.y); w2_ = bfs2f(u.z); w3_ = bfs2f(u.w);
      } else {
        float4 fv = *(const float4*)((const float*)Wfv + wi);
        w0 = fv.x; w1_ = fv.y; w2_ = fv.z; w3_ = fv.w;
      }
      float s = w1b[f];
      v0 += s * w0; v1 += s * w1_; v2 += s * w2_; v3 += s * w3_;
    }
    ushort4 o;
    o.x = (unsigned short)f2bf(v0); o.y = (unsigned short)f2bf(v1);
    o.z = (unsigned short)f2bf(v2); o.w = (unsigned short)f2bf(v3);
    *(ushort4*)(W1eff + (size_t)n * D_MODEL + k0) = o;
  }
}

// ---------------------------------------------------------------------------
// Kernel 2: split-K GEMM partials, ONE OUTPUT TILE PER WAVE.
// R6-R7 established: neither barriers, nor A-pattern, nor TLP alone is the
// limiter. Remaining mechanism: per-wave dependent-load chain — R5/R7 k-loops
// need 4 divergent B-loads (16x64B L2 txns each) per MFMA quad; hiding 200cy
// L2 latency needs ~160 B-prefetch VGPRs -> impossible -> ~150cy stall/step.
// Fix: block = 4 waves x 16 SHARED tokens; wave w owns cols [16w,+16) only.
//   - A strip (16 KB) staged cooperatively: 4 gload_lds per wave (shallow
//     DMA queue, m97-style), fill-shaped 1KB row-slices, source-XOR swizzle
//     (R5/R7-proven bytes), one barrier.
//   - k-loop: 16 x {1 swizzled ds_read_b128 + ONE 16B B-load + ONE MFMA}.
//     Prefetch depth needed drops 4x (~8 loads = 32 VGPR - fits);
//     launch_bounds(256,6) -> 24 waves/CU TLP on top.
// Grid 4096 = t*8 + c -> XCD = c (B-chunk L2-hot per XCD).
// MFMA 16x16x32 bf16: A[m=lane&15][k=8*(lane>>4)+j]; C: col=lane&15,
// row=(lane>>4)*4+reg (m89/m91-verified). Wave w's B row = w*16+m -> output
// col = w*16+m; store part[c][tok][col] matches delta_ep (unchanged).
// ---------------------------------------------------------------------------
__global__ __launch_bounds__(256, 6) void gemm_part(const void* __restrict__ hid,
                                                    const short* __restrict__ B_,
                                                    float* __restrict__ part) {
  int t = blockIdx.x >> 3;          // 16-token tile 0..511
  int c = blockIdx.x & 7;           // K-chunk 0..7 (XCD = c)
  int w    = threadIdx.x >> 6;      // wave 0..3 = col tile
  int lane = threadIdx.x & 63;
  int m = lane & 15, kg = lane >> 4;

  __shared__ short As[16 * 512];    // 16 KB: row-major 1KB rows, unit-XOR swz

  int fhid = sniff_wave((const unsigned short*)hid, NTOK * D_MODEL);

  f32x4 acc = {0.f, 0.f, 0.f, 0.f};
  const short* Bp = B_ + (size_t)(w * 16 + m) * D_MODEL + c * 512 + kg * 8;

  if (fhid) {  // hidden bf16 (confirmed path)
    // ---- cooperative stage: wave w stages rows [w*4, w*4+4) ----
#pragma unroll
    for (int i = 0; i < 4; ++i) {
      int n = w * 4 + i;            // strip row 0..15 (wave-uniform)
      const char* src = (const char*)hid +
          ((size_t)(t * 16 + n) * D_MODEL + c * 512) * 2 +
          ((lane ^ (n & 7)) * 16);
      gload_lds16(src, (char*)As + n * 1024);
    }
    __syncthreads();                // drains vmcnt -> strip ready
#pragma unroll
    for (int s = 0; s < 16; ++s) {
      int u = s * 4 + kg;                         // logical 16B unit 0..63
      bf16x8 a = *(const bf16x8*)((const char*)As + m * 1024 +
                                  ((u ^ (m & 7)) * 16));
      bf16x8 b = *(const bf16x8*)(Bp + s * 32);
      acc = __builtin_amdgcn_mfma_f32_16x16x32_bf16(a, b, acc, 0, 0, 0);
    }
  } else {     // hidden f32 fallback (correctness path, demand loads)
    const float* Ap = (const float*)hid +
        (size_t)(t * 16 + m) * D_MODEL + c * 512 + kg * 8;
    for (int s = 0; s < 16; ++s) {
      float4 lo = *(const float4*)(Ap + s * 32);
      float4 hi = *(const float4*)(Ap + s * 32 + 4);
      bf16x8 a;
      a[0] = f2bf(lo.x); a[1] = f2bf(lo.y); a[2] = f2bf(lo.z); a[3] = f2bf(lo.w);
      a[4] = f2bf(hi.x); a[5] = f2bf(hi.y); a[6] = f2bf(hi.z); a[7] = f2bf(hi.w);
      bf16x8 b = *(const bf16x8*)(Bp + s * 32);
      acc = __builtin_amdgcn_mfma_f32_16x16x32_bf16(a, b, acc, 0, 0, 0);
    }
  }

  // ---- store partials: part[c][token][w*16+m] (fire-and-forget) ----
  float* po = part + ((size_t)c * NTOK + (size_t)t * 16) * 64;
#pragma unroll
  for (int r = 0; r < 4; ++r) {
    int row = kg * 4 + r;
    po[row * 64 + w * 16 + m] = acc[r];
  }
}

// ---------------------------------------------------------------------------
// Kernel 3: reduce 8 K-chunk partials + b1, exact GELU, dot W2, softplus.
// Grid 512, block 256 thr: 16 tokens; thread = (token 0..15) x (cid 0..15).
// ---------------------------------------------------------------------------
__global__ __launch_bounds__(256) void delta_ep(const float* __restrict__ part,
                                                const void* __restrict__ b1,
                                                const void* __restrict__ w2,
                                                const void* __restrict__ b2p,
                                                float* __restrict__ delta) {
  int tok = blockIdx.x * 16 + (threadIdx.x >> 4);
  int cid = threadIdx.x & 15;
  int fb1 = sniff_wave((const unsigned short*)b1, 64);
  int fw2 = sniff_wave((const unsigned short*)w2, 64);
  float y = 0.f;
#pragma unroll
  for (int j = 0; j < 4; ++j) {
    int col = cid + 16 * j;
    float s = 0.f;
#pragma unroll
    for (int c = 0; c < 8; ++c)
      s += part[((size_t)c * NTOK + tok) * 64 + col];
    s += fb1 ? bf2f(b1, col) : ((const float*)b1)[col];
    float g = 0.5f * s * (1.0f + erff(s * 0.70710678118654752f));  // exact GELU
    y += g * (fw2 ? bf2f(w2, col) : ((const float*)w2)[col]);
  }
#pragma unroll
  for (int off = 1; off <= 8; off <<= 1) y += __shfl_xor(y, off, 64);
  if (cid == 0) {
    float x = y + decode_b2(b2p);
    float d = (x > 20.0f) ? x : log1pf(expf(x));  // softplus
    delta[tok] = d;
  }
}

// ---------------------------------------------------------------------------
// Kernel 4: causal EMA, gate, field, mean. OUTPUT IS FLOAT32 (mixed tuple
// (bf16,bf16,f32) concatenated by harness -> numpy-promoted f32).
// ---------------------------------------------------------------------------
__global__ __launch_bounds__(256) void ema_out(const float* __restrict__ delta,
                                               const void* __restrict__ lamp,
                                               float* __restrict__ out) {
  int b    = threadIdx.x >> 6;   // batch 0..3
  int lane = threadIdx.x & 63;
  const float alpha = 0.9f;
  float d[32];
  const float* dp = delta + b * SEQ + lane * 32;
  float beta = 0.f, lsum = 0.f;
#pragma unroll
  for (int i = 0; i < 32; ++i) {
    d[i] = dp[i];
    lsum += d[i];
    beta = alpha * beta + 0.1f * d[i];
  }
  float accA = 0.03433683820292512f;  // 0.9^32
  float accB = beta;
  for (int off = 1; off < 64; off <<= 1) {
    float uA = __shfl_up(accA, off, 64);
    float uB = __shfl_up(accB, off, 64);
    if (lane >= off) {
      accB = accB + accA * uB;  // cur o prev
      accA = accA * uA;
    }
  }
  float prev = __shfl_up(accB, 1, 64);
  float h = (lane == 0) ? 0.f : prev;  // carry-in state for this chunk
  float lam = decode_lam(lamp);
#pragma unroll
  for (int i = 0; i < 32; ++i) {
    h = alpha * h + 0.1f * d[i];
    float gate = 1.0f / (1.0f + expf(lam * h));  // sigmoid(-lam*h)
    out[b * SEQ + lane * 32 + i]        = gate;
    out[NTOK + b * SEQ + lane * 32 + i] = h;
  }
#pragma unroll
  for (int off = 32; off >= 1; off >>= 1) lsum += __shfl_xor(lsum, off, 64);
  __shared__ float bs[4];
  if (lane == 0) bs[b] = lsum;
  __syncthreads();
  if (threadIdx.x == 0)
    out[2 * NTOK] = (bs[0] + bs[1] + bs[2] + bs[3]) * (1.0f / 8192.0f);
}

// ---------------------------------------------------------------------------
extern "C" void kernel_launch(void* const* d_in, const int* in_sizes, int n_in,
                              void* d_out, int out_size, void* d_ws, size_t ws_size,
                              hipStream_t stream) {
  const void* hidden = d_in[0];  // [4,2048,4096]
  const void* Wf     = d_in[1];  // [16,4096]
  const void* W1     = d_in[2];  // [64,4112]
  const void* b1     = d_in[3];  // [64]
  const void* W2     = d_in[4];  // [1,64]
  const void* b2     = d_in[5];  // [1]
  const void* lam    = d_in[6];  // [1]
  float* out = (float*)d_out;    // 16385 f32 (gate 8192 | field 8192 | mean 1)

  // ws: [0, 512K) W1eff bf16, [512K, +32K) delta f32, then part f32
  // [8][8192][64] = 16 MB.
  char* ws = (char*)d_ws;
  short* W1eff = (short*)ws;
  float* delta = (float*)(ws + (size_t)64 * D_MODEL * 2);
  float* part  = (float*)(ws + (size_t)64 * D_MODEL * 2 + NTOK * 4);

  fold_w1<<<64, 256, 0, stream>>>(W1, Wf, W1eff);
  gemm_part<<<4096, 256, 0, stream>>>(hidden, W1eff, part);
  delta_ep<<<512, 256, 0, stream>>>(part, b1, W2, b2, delta);
  ema_out<<<1, 256, 0, stream>>>(delta, lam, out);
}

// Round 9
// 228.073 us; speedup vs baseline: 1.1503x; 1.1503x over previous
//
#include <hip/hip_runtime.h>
#include <hip/hip_bf16.h>

#define D_MODEL 4096
#define NTOK    8192   // B*S = 4*2048
#define SEQ     2048
#define NCHUNK  16     // K-chunks of 256 cols
#define KC      256

typedef short bf16x8 __attribute__((ext_vector_type(8)));  // 8 bf16 in 4 VGPRs
typedef float f32x4  __attribute__((ext_vector_type(4)));

__device__ __forceinline__ short f2bf(float x) {
  __hip_bfloat16 h = __float2bfloat16(x);
  return *reinterpret_cast<short*>(&h);
}
__device__ __forceinline__ float bfs2f(unsigned short u) {
  unsigned int x = ((unsigned int)u) << 16;
  float f;
  __builtin_memcpy(&f, &x, 4);
  return f;
}
__device__ __forceinline__ float bf2f(const void* p, size_t i) {
  return bfs2f(((const unsigned short*)p)[i]);
}

// Async global->LDS, 16B per lane. LDS dest is the WAVE-UNIFORM base
// (HW adds lane*16); global src is per-lane (guide m104/m173).
__device__ __forceinline__ void gload_lds16(const void* g, void* l) {
  __builtin_amdgcn_global_load_lds(
      (__attribute__((address_space(1))) void*)(g),
      (__attribute__((address_space(3))) void*)(l), 16, 0, 0);
}

// ---------------------------------------------------------------------------
// Wave-level dtype sniff (confirmed: hidden=bf16, weights=f32; kept for
// robustness). Returns 1 -> bf16[], 0 -> float[]. Wave-uniform result.
// ---------------------------------------------------------------------------
__device__ __forceinline__ int sniff_wave(const unsigned short* p, int n) {
  int lane = threadIdx.x & 63;
  int S = n / 2 < 64 ? n / 2 : 64;
  bool act = lane < S;
  unsigned short ve = 0, vo = 0;
  if (act) { ve = p[2 * lane]; vo = p[2 * lane + 1]; }
  int ee = (ve >> 7) & 0xFF, eo = (vo >> 7) & 0xFF;
  bool ve_band   = (ve == 0) || (ve == 0x8000) || (ee >= 96 && ee <= 141);
  bool vo_bandnz = (vo != 0) && (vo != 0x8000) && (eo >= 96 && eo <= 141);
  int zp = __popcll(__ballot(act && ve == 0 && vo == 0));
  int ob = __popcll(__ballot(act && ve == 0 && vo_bandnz));
  int eb = __popcll(__ballot(act && ve_band));
  if (zp == S) return 1;
  if (4 * ob >= 3 * S) return 0;   // f32 storage of bf16-rounded values
  if (4 * eb >= 3 * S) return 1;   // true bf16
  return 0;                        // raw f32
}

__device__ __forceinline__ float decode_lam(const void* lamp) {
  unsigned short l0 = *(const unsigned short*)lamp;
  int le = (l0 >> 7) & 0xFF;
  if (l0 != 0 && l0 != 0x8000 && le >= 96 && le <= 141)
    return bfs2f(l0);
  return *(const float*)lamp;
}
__device__ __forceinline__ float decode_b2(const void* p) {
  unsigned short c0 = *(const unsigned short*)p;
  int ce = (c0 >> 7) & 0xFF;
  if (c0 == 0) return 0.0f;
  if (c0 != 0x8000 && ce >= 96 && ce <= 141)
    return bfs2f(c0);
  return *(const float*)p;
}

// ---------------------------------------------------------------------------
// Kernel 1: fold W_fiber into W1 -> W1_eff[64][4096] bf16 (vectorized).
// ---------------------------------------------------------------------------
__global__ __launch_bounds__(256) void fold_w1(const void* __restrict__ W1v,
                                               const void* __restrict__ Wfv,
                                               short* __restrict__ W1eff) {
  int n = blockIdx.x;  // 0..63
  int fw1 = sniff_wave((const unsigned short*)W1v, 64 * 4112);
  int fwf = sniff_wave((const unsigned short*)Wfv, 16 * D_MODEL);
  __shared__ float w1b[16];
  if (threadIdx.x < 16) {
    size_t idx = (size_t)n * 4112 + 4096 + threadIdx.x;
    w1b[threadIdx.x] = fw1 ? bf2f(W1v, idx) : ((const float*)W1v)[idx];
  }
  __syncthreads();
  for (int it = 0; it < 4; ++it) {
    int k0 = it * 1024 + threadIdx.x * 4;
    size_t idx = (size_t)n * 4112 + k0;
    float v0, v1, v2, v3;
    if (fw1) {
      ushort4 u = *(const ushort4*)((const unsigned short*)W1v + idx);
      v0 = bfs2f(u.x); v1 = bfs2f(u.y); v2 = bfs2f(u.z); v3 = bfs2f(u.w);
    } else {
      float4 f = *(const float4*)((const float*)W1v + idx);
      v0 = f.x; v1 = f.y; v2 = f.z; v3 = f.w;
    }
#pragma unroll
    for (int f = 0; f < 16; ++f) {
      size_t wi = (size_t)f * D_MODEL + k0;
      float w0, w1_, w2_, w3_;
      if (fwf) {
        ushort4 u = *(const ushort4*)((const unsigned short*)Wfv + wi);
        w0 = bfs2f(u.x); w1_ = bfs2f(u.y); w2_ = bfs2f(u.z); w3_ = bfs2f(u.w);
      } else {
        float4 fv = *(const float4*)((const float*)Wfv + wi);
        w0 = fv.x; w1_ = fv.y; w2_ = fv.z; w3_ = fv.w;
      }
      float s = w1b[f];
      v0 += s * w0; v1 += s * w1_; v2 += s * w2_; v3 += s * w3_;
    }
    ushort4 o;
    o.x = (unsigned short)f2bf(v0); o.y = (unsigned short)f2bf(v1);
    o.z = (unsigned short)f2bf(v2); o.w = (unsigned short)f2bf(v3);
    *(ushort4*)(W1eff + (size_t)n * D_MODEL + k0) = o;
  }
}

// ---------------------------------------------------------------------------
// Kernel 2: split-K GEMM partials — BOTH operands staged via coalesced
// gload_lds (L2 request-rate fix, see round theory).
// Grid 2048 = t*16 + c (t = 64-token tile 0..127, c = K-chunk 0..15,
// XCD = c&7 -> each XCD keeps its two 32KB B-chunks L2-hot).
// Block 256 thr (4 waves), 64 KB LDS -> 2 blocks/CU.
//   A: wave w stages its OWN 16-row strip (16 rows x 512B slice = 8 KB) in
//      8 coalesced gload_lds (2 rows per 1KB instr, source-XOR swizzle).
//   B: wave w stages B rows [w*16,+16) the same way into the shared 32 KB
//      B buffer -> B read from HBM/L2 ONCE per block (vs per-wave divergent
//      loads = 16 L2 txns/instr in R5-R8; ~4.2M 64B requests -> ~0.5M 128B).
//   One vmcnt(0) + barrier; then 8 k-steps x {5 swizzled conflict-free
//   ds_read_b128 (1 A + 4 B) + 4 independent MFMA chains}.
// MFMA 16x16x32 bf16: A[m=lane&15][k=8*(lane>>4)+j]; C: col=lane&15,
// row=(lane>>4)*4+reg (m89/m91-verified; store layout identical to R5).
// ---------------------------------------------------------------------------
__global__ __launch_bounds__(256, 2) void gemm_part(const void* __restrict__ hid,
                                                    const short* __restrict__ B_,
                                                    float* __restrict__ part) {
  int t = blockIdx.x >> 4;          // M-tile 0..127 (64 rows each)
  int c = blockIdx.x & 15;          // K-chunk 0..15 (XCD = c&7)
  int w    = threadIdx.x >> 6;      // wave 0..3
  int lane = threadIdx.x & 63;
  int m = lane & 15, kg = lane >> 4;

  __shared__ char smem[65536];      // [0,32K) A strips; [32K,64K) B chunk
  char* As  = smem;                 // wave w strip at w*8192, rows at 512B pitch
  char* Bsm = smem + 32768;         // B row n at (n>>4)*8192 + (n&15)*512

  int fhid = sniff_wave((const unsigned short*)hid, NTOK * D_MODEL);

  // ---- stage B rows [w*16,+16): 8 coalesced instrs (2 rows per 1KB) ----
#pragma unroll
  for (int j = 0; j < 8; ++j) {
    int row = w * 16 + 2 * j + (lane >> 5);      // per-lane (2 rows/instr)
    const char* src = (const char*)B_ + (size_t)row * (D_MODEL * 2) + c * 512 +
                      (((lane & 31) ^ (row & 7)) * 16);
    gload_lds16(src, Bsm + w * 8192 + j * 1024); // uniform base; HW +lane*16
  }

  if (fhid) {
    // ---- stage own A strip: 8 coalesced instrs ----
#pragma unroll
    for (int i = 0; i < 8; ++i) {
      int row = w * 16 + 2 * i + (lane >> 5);    // strip row 0..63
      const char* src = (const char*)hid +
          ((size_t)(t * 64 + row) * D_MODEL + c * KC) * 2 +
          (((lane & 31) ^ (row & 7)) * 16);
      gload_lds16(src, As + w * 8192 + i * 1024);
    }
  }
  asm volatile("s_waitcnt vmcnt(0)" ::: "memory");
  __syncthreads();                   // B (and A) visible to all waves

  f32x4 acc0 = {0.f, 0.f, 0.f, 0.f};
  f32x4 acc1 = acc0, acc2 = acc0, acc3 = acc0;

  if (fhid) {  // hidden bf16 (confirmed path)
#pragma unroll
    for (int s = 0; s < 8; ++s) {
      int u  = s * 4 + kg;                       // logical 16B unit 0..31
      int sw = ((u ^ (m & 7)) * 16);             // swizzled slot byte
      bf16x8 a  = *(const bf16x8*)(As  + w * 8192 + m * 512 + sw);
      bf16x8 b0 = *(const bf16x8*)(Bsm + 0 * 8192 + m * 512 + sw);
      bf16x8 b1 = *(const bf16x8*)(Bsm + 1 * 8192 + m * 512 + sw);
      bf16x8 b2 = *(const bf16x8*)(Bsm + 2 * 8192 + m * 512 + sw);
      bf16x8 b3 = *(const bf16x8*)(Bsm + 3 * 8192 + m * 512 + sw);
      acc0 = __builtin_amdgcn_mfma_f32_16x16x32_bf16(a, b0, acc0, 0, 0, 0);
      acc1 = __builtin_amdgcn_mfma_f32_16x16x32_bf16(a, b1, acc1, 0, 0, 0);
      acc2 = __builtin_amdgcn_mfma_f32_16x16x32_bf16(a, b2, acc2, 0, 0, 0);
      acc3 = __builtin_amdgcn_mfma_f32_16x16x32_bf16(a, b3, acc3, 0, 0, 0);
    }
  } else {     // hidden f32 fallback (correctness path; B from staged LDS)
    const float* Ap = (const float*)hid +
        (size_t)(t * 64 + w * 16 + m) * D_MODEL + c * KC + kg * 8;
    for (int s = 0; s < 8; ++s) {
      float4 lo = *(const float4*)(Ap + s * 32);
      float4 hi = *(const float4*)(Ap + s * 32 + 4);
      bf16x8 a;
      a[0] = f2bf(lo.x); a[1] = f2bf(lo.y); a[2] = f2bf(lo.z); a[3] = f2bf(lo.w);
      a[4] = f2bf(hi.x); a[5] = f2bf(hi.y); a[6] = f2bf(hi.z); a[7] = f2bf(hi.w);
      int u  = s * 4 + kg;
      int sw = ((u ^ (m & 7)) * 16);
      bf16x8 b0 = *(const bf16x8*)(Bsm + 0 * 8192 + m * 512 + sw);
      bf16x8 b1 = *(const bf16x8*)(Bsm + 1 * 8192 + m * 512 + sw);
      bf16x8 b2 = *(const bf16x8*)(Bsm + 2 * 8192 + m * 512 + sw);
      bf16x8 b3 = *(const bf16x8*)(Bsm + 3 * 8192 + m * 512 + sw);
      acc0 = __builtin_amdgcn_mfma_f32_16x16x32_bf16(a, b0, acc0, 0, 0, 0);
      acc1 = __builtin_amdgcn_mfma_f32_16x16x32_bf16(a, b1, acc1, 0, 0, 0);
      acc2 = __builtin_amdgcn_mfma_f32_16x16x32_bf16(a, b2, acc2, 0, 0, 0);
      acc3 = __builtin_amdgcn_mfma_f32_16x16x32_bf16(a, b3, acc3, 0, 0, 0);
    }
  }

  // ---- store partials: part[c][token][col] (fire-and-forget) ----
  float* po = part + ((size_t)c * NTOK + (size_t)t * 64 + w * 16) * 64;
#pragma unroll
  for (int r = 0; r < 4; ++r) {
    int row = kg * 4 + r;
    po[row * 64 + (m +  0)] = acc0[r];
    po[row * 64 + (m + 16)] = acc1[r];
    po[row * 64 + (m + 32)] = acc2[r];
    po[row * 64 + (m + 48)] = acc3[r];
  }
}

// ---------------------------------------------------------------------------
// Kernel 3: reduce 16 K-chunk partials + b1, exact GELU, dot W2, softplus.
// Grid 512, block 256 thr: 16 tokens; thread = (token 0..15) x (cid 0..15).
// ---------------------------------------------------------------------------
__global__ __launch_bounds__(256) void delta_ep(const float* __restrict__ part,
                                                const void* __restrict__ b1,
                                                const void* __restrict__ w2,
                                                const void* __restrict__ b2p,
                                                float* __restrict__ delta) {
  int tok = blockIdx.x * 16 + (threadIdx.x >> 4);
  int cid = threadIdx.x & 15;
  int fb1 = sniff_wave((const unsigned short*)b1, 64);
  int fw2 = sniff_wave((const unsigned short*)w2, 64);
  float y = 0.f;
#pragma unroll
  for (int j = 0; j < 4; ++j) {
    int col = cid + 16 * j;
    float s = 0.f;
#pragma unroll
    for (int c = 0; c < NCHUNK; ++c)
      s += part[((size_t)c * NTOK + tok) * 64 + col];
    s += fb1 ? bf2f(b1, col) : ((const float*)b1)[col];
    float g = 0.5f * s * (1.0f + erff(s * 0.70710678118654752f));  // exact GELU
    y += g * (fw2 ? bf2f(w2, col) : ((const float*)w2)[col]);
  }
#pragma unroll
  for (int off = 1; off <= 8; off <<= 1) y += __shfl_xor(y, off, 64);
  if (cid == 0) {
    float x = y + decode_b2(b2p);
    float d = (x > 20.0f) ? x : log1pf(expf(x));  // softplus
    delta[tok] = d;
  }
}

// ---------------------------------------------------------------------------
// Kernel 4: causal EMA, gate, field, mean. OUTPUT IS FLOAT32 (mixed tuple
// (bf16,bf16,f32) concatenated by harness -> numpy-promoted f32).
// ---------------------------------------------------------------------------
__global__ __launch_bounds__(256) void ema_out(const float* __restrict__ delta,
                                               const void* __restrict__ lamp,
                                               float* __restrict__ out) {
  int b    = threadIdx.x >> 6;   // batch 0..3
  int lane = threadIdx.x & 63;
  const float alpha = 0.9f;
  float d[32];
  const float* dp = delta + b * SEQ + lane * 32;
  float beta = 0.f, lsum = 0.f;
#pragma unroll
  for (int i = 0; i < 32; ++i) {
    d[i] = dp[i];
    lsum += d[i];
    beta = alpha * beta + 0.1f * d[i];
  }
  float accA = 0.03433683820292512f;  // 0.9^32
  float accB = beta;
  for (int off = 1; off < 64; off <<= 1) {
    float uA = __shfl_up(accA, off, 64);
    float uB = __shfl_up(accB, off, 64);
    if (lane >= off) {
      accB = accB + accA * uB;  // cur o prev
      accA = accA * uA;
    }
  }
  float prev = __shfl_up(accB, 1, 64);
  float h = (lane == 0) ? 0.f : prev;  // carry-in state for this chunk
  float lam = decode_lam(lamp);
#pragma unroll
  for (int i = 0; i < 32; ++i) {
    h = alpha * h + 0.1f * d[i];
    float gate = 1.0f / (1.0f + expf(lam * h));  // sigmoid(-lam*h)
    out[b * SEQ + lane * 32 + i]        = gate;
    out[NTOK + b * SEQ + lane * 32 + i] = h;
  }
#pragma unroll
  for (int off = 32; off >= 1; off >>= 1) lsum += __shfl_xor(lsum, off, 64);
  __shared__ float bs[4];
  if (lane == 0) bs[b] = lsum;
  __syncthreads();
  if (threadIdx.x == 0)
    out[2 * NTOK] = (bs[0] + bs[1] + bs[2] + bs[3]) * (1.0f / 8192.0f);
}

// ---------------------------------------------------------------------------
extern "C" void kernel_launch(void* const* d_in, const int* in_sizes, int n_in,
                              void* d_out, int out_size, void* d_ws, size_t ws_size,
                              hipStream_t stream) {
  const void* hidden = d_in[0];  // [4,2048,4096]
  const void* Wf     = d_in[1];  // [16,4096]
  const void* W1     = d_in[2];  // [64,4112]
  const void* b1     = d_in[3];  // [64]
  const void* W2     = d_in[4];  // [1,64]
  const void* b2     = d_in[5];  // [1]
  const void* lam    = d_in[6];  // [1]
  float* out = (float*)d_out;    // 16385 f32 (gate 8192 | field 8192 | mean 1)

  // ws: [0, 512K) W1eff bf16, [512K, +32K) delta f32, then part f32
  // [16][8192][64] = 32 MB.
  char* ws = (char*)d_ws;
  short* W1eff = (short*)ws;
  float* delta = (float*)(ws + (size_t)64 * D_MODEL * 2);
  float* part  = (float*)(ws + (size_t)64 * D_MODEL * 2 + NTOK * 4);

  fold_w1<<<64, 256, 0, stream>>>(W1, Wf, W1eff);
  gemm_part<<<2048, 256, 0, stream>>>(hidden, W1eff, part);
  delta_ep<<<512, 256, 0, stream>>>(part, b1, W2, b2, delta);
  ema_out<<<1, 256, 0, stream>>>(delta, lam, out);
}